// Round 12
// baseline (344.785 us; speedup 1.0000x reference)
//
#include <hip/hip_runtime.h>
#include <hip/hip_bf16.h>

#define D 8
#define L 12
#define C 9
#define W 128
#define B 4096
#define EPS 1e-5f

typedef __attribute__((ext_vector_type(8))) short v8s;   // 8 x bf16
typedef __attribute__((ext_vector_type(4))) float v4f;   // 4 x f32 acc

// Workspace layout (in floats)
#define OFF_STATS 0        // [64 slices][18] per-slice partials (sum[9], sumsq[9])
#define OFF_B1E   1152     // fp32 [D][32] folded conv1 bias
#define OFF_W1T   1408     // bf16 [D][32 o][10 tap][16 c]  = 40960 halfs
#define OFF_W2T   21888    // bf16 [D][64 o][9 tap][32 ic]  = 147456 halfs
#define OFF_FCWP  95616    // bf16 [D][12 l][1664 k=p*64+o] = 159744 halfs

// Per-ROW LDS region (shorts), 2 regions per block:
//   xb  [2 ql][144 row][8] = 2304 @0   (h2p[1672] + aliases after conv1)
//   h1t [4 icq][73 row][8] = 2336 @2304 (red f32 aliases after conv2)
#define REGION 4640
#define H1OFF  2304

__device__ inline unsigned short f2bf(float f) {
    unsigned u = __builtin_bit_cast(unsigned, f);
    u += 0x7FFFu + ((u >> 16) & 1u);                 // round-nearest-even
    return (unsigned short)(u >> 16);
}
__device__ inline unsigned pk2(float a, float b) {
    float2 f2; f2.x = a; f2.y = b;
    __hip_bfloat162 h = __float22bfloat162_rn(f2);   // v_cvt_pk_bf16_f32
    unsigned u; __builtin_memcpy(&u, &h, 4);
    return u;
}

// ---------------------------------------------------------------------------
// Kernel 1: stats partials (0..575) + w2t/fcwp repack (576..615) + out zero
// (616..623).
// ---------------------------------------------------------------------------
__global__ void stats_repack_kernel(const float* __restrict__ x,
                                    const float* __restrict__ w2,
                                    const float* __restrict__ fcw,
                                    float* __restrict__ ws,
                                    float* __restrict__ out) {
    const int t = threadIdx.x;
    __shared__ float redS[8];
    if (blockIdx.x < 576) {
        const int c = blockIdx.x % 9;
        const int slice = blockIdx.x / 9;
        const int w4 = t & 31, br = t >> 5;
        const float4* x4 = (const float4*)x;
        float s = 0.f, s2 = 0.f;
        for (int b = slice * 8 + br; b < B; b += 64 * 8) {
            float4 v = x4[(size_t)b * 288 + c * 32 + w4];
            s  += v.x + v.y + v.z + v.w;
            s2 += v.x * v.x + v.y * v.y + v.z * v.z + v.w * v.w;
        }
        for (int off = 32; off >= 1; off >>= 1) {
            s  += __shfl_down(s, off);
            s2 += __shfl_down(s2, off);
        }
        if ((t & 63) == 0) { redS[(t >> 6) * 2] = s; redS[(t >> 6) * 2 + 1] = s2; }
        __syncthreads();
        if (t == 0) {
            ws[OFF_STATS + slice * 18 + c]     = redS[0] + redS[2] + redS[4] + redS[6];
            ws[OFF_STATS + slice * 18 + 9 + c] = redS[1] + redS[3] + redS[5] + redS[7];
        }
    } else if (blockIdx.x < 616) {
        const int i0 = blockIdx.x - 576;
        const int d = i0 / 5, part = i0 % 5;
        short* w2t  = (short*)(ws + OFF_W2T);
        short* fcwp = (short*)(ws + OFF_FCWP);
        if (part < 2) {
            for (int i = part * 256 + t; i < 64 * 9 * 32; i += 512) {
                int o = i / 288, r = i % 288, tap = r / 32, ic = r & 31;
                w2t[(size_t)d * 18432 + i] =
                    (short)f2bf(w2[(((size_t)(d * 64 + o)) * 32 + ic) * 9 + tap]);
            }
        } else {
            for (int i = (part - 2) * 256 + t; i < 12 * 1664; i += 768) {
                int l = i / 1664, k = i % 1664, p = k >> 6, o = k & 63;
                fcwp[((size_t)d * 12) * 1664 + i] =
                    (short)f2bf(fcw[((size_t)(d * 12 + l)) * 1664 + o * 26 + p]);
            }
        }
    } else {
        const int base = (blockIdx.x - 616) * 6144;
        float4 z; z.x = z.y = z.z = z.w = 0.f;
        float4* o4 = (float4*)(out + base);
        for (int i = t; i < 1536; i += 256) o4[i] = z;
    }
}

// ---------------------------------------------------------------------------
// Kernel 2: reduce slice partials -> BN scale/shift; fold into conv1 weights.
// ---------------------------------------------------------------------------
__global__ void fold1_kernel(const float* __restrict__ w1, const float* __restrict__ b1,
                             const float* __restrict__ gamma, const float* __restrict__ beta,
                             float* __restrict__ ws) {
    const int d = blockIdx.x, t = threadIdx.x;
    __shared__ float g[9], bt[9];
    if (t < 64) {
        for (int c = 0; c < 9; c++) {
            float s  = ws[OFF_STATS + t * 18 + c];
            float s2 = ws[OFF_STATS + t * 18 + 9 + c];
            for (int off = 32; off >= 1; off >>= 1) {
                s  += __shfl_down(s, off);
                s2 += __shfl_down(s2, off);
            }
            if (t == 0) {
                const float N = (float)B * (float)W;
                float m  = s / N;
                float vv = s2 / N - m * m;
                float inv = rsqrtf(vv + EPS);
                float gg = gamma[d * 9 + c] * inv;
                g[c] = gg; bt[c] = beta[d * 9 + c] - gg * m;
            }
        }
    }
    __syncthreads();
    const int o = t >> 3, sub = t & 7;
    short* w1t = (short*)(ws + OFF_W1T);
    short* dst = w1t + (size_t)d * 5120 + o * 160;
    const float* src = w1 + ((size_t)(d * 32 + o)) * 81;
    float bias_part = 0.f;
    for (int tap = sub; tap < 10; tap += 8) {
        for (int c = 0; c < 16; c++) {
            float v = 0.f;
            if (tap < 9 && c < 9) {
                float wv = src[c * 9 + tap];
                v = wv * g[c];
                bias_part += wv * bt[c];
            }
            dst[tap * 16 + c] = (short)f2bf(v);
        }
    }
    bias_part += __shfl_xor(bias_part, 1);
    bias_part += __shfl_xor(bias_part, 2);
    bias_part += __shfl_xor(bias_part, 4);
    if (sub == 0) ws[OFF_B1E + d * 32 + o] = b1[d * 32 + o] + bias_part;
}

// ---------------------------------------------------------------------------
// Kernel 3: the branch. Grid (B/2, D); block = 2 batch rows x 1 domain,
// 256 threads = 4 waves: wave wv -> row r=wv>>1, position-half h=wv&1.
// Halving per-wave accumulators (conv1 acc[4][2], conv2 acc[2][4] = 32 AGPR)
// cuts regs/wave 128 -> ~95 so 5 blocks/CU fit (20 waves, +25% vs R11's 16).
// Position-split keeps LDS A-read traffic per row unchanged; only global
// weight loads duplicate (L1/L2-hot). 4 block barriers.
// __launch_bounds__(256,5): cap 102 regs vs ~95 need. (NEVER (256,6): R8.)
// ---------------------------------------------------------------------------
__global__ __launch_bounds__(256, 5)
void branch_kernel(const float* __restrict__ x,
                   const float* __restrict__ b2g,
                   const float* __restrict__ fcb,
                   const float* __restrict__ wts,
                   const float* __restrict__ ws,
                   float* __restrict__ out) {
    const int t = threadIdx.x;
    const int lane = t & 63;
    const int wv = t >> 6;                       // 0..3
    const int r  = wv >> 1;                      // row within block
    const int h  = wv & 1;                       // position half
    const int d = blockIdx.y;
    const int b0 = blockIdx.x * 2;
    const short* w1t  = (const short*)(ws + OFF_W1T) + (size_t)d * 5120;
    const short* w2t  = (const short*)(ws + OFF_W2T) + (size_t)d * 18432;
    const short* fcwp = (const short*)(ws + OFF_FCWP) + (size_t)d * 12 * 1664;
    const float* b1e  = ws + OFF_B1E + d * 32;

    __shared__ __align__(16) short lds[2 * REGION];   // 18560 B
    short* myrow = &lds[r * REGION];

    const int n = lane & 15, quad = lane >> 4;

    // ---- phase 1: stage own half of row r (w = lane + h*64) ----
    {
        const float* xrow = x + (size_t)(b0 + r) * 1152;
        const int w = lane + h * 64;
        float v[9];
        #pragma unroll
        for (int c = 0; c < 9; c++) v[c] = xrow[c * 128 + w];
        uint4 lo, hi;
        lo.x = pk2(v[0], v[1]); lo.y = pk2(v[2], v[3]);
        lo.z = pk2(v[4], v[5]); lo.w = pk2(v[6], v[7]);
        hi.x = (unsigned)(unsigned short)f2bf(v[8]); hi.y = 0; hi.z = 0; hi.w = 0;
        *(uint4*)&myrow[(0 * 144 + w) * 8] = lo;
        *(uint4*)&myrow[(1 * 144 + w) * 8] = hi;
        if (h == 0 && lane < 16) {   // zero pad rows 128..143, both ql planes
            uint4 z; z.x = z.y = z.z = z.w = 0;
            *(uint4*)&myrow[(0 * 144 + 128 + lane) * 8] = z;
            *(uint4*)&myrow[(1 * 144 + 128 + lane) * 8] = z;
        }
    }
    __syncthreads();

    // ---- phase 2: conv1, raw positions 64h..64h+63 (mt' = h*4+mt) ----
    {
        const int qh = quad >> 1, ql = quad & 1;
        const float bias0 = b1e[n], bias1 = b1e[16 + n];
        v4f acc[4][2];
        #pragma unroll
        for (int mt = 0; mt < 4; mt++)
            #pragma unroll
            for (int nt = 0; nt < 2; nt++) { v4f z = {0.f,0.f,0.f,0.f}; acc[mt][nt] = z; }
        #pragma unroll
        for (int s = 0; s < 5; s++) {
            v8s Bw0 = *(const v8s*)&w1t[n * 160 + (2 * s + qh) * 16 + ql * 8];
            v8s Bw1 = *(const v8s*)&w1t[(16 + n) * 160 + (2 * s + qh) * 16 + ql * 8];
            #pragma unroll
            for (int mt = 0; mt < 4; mt++) {
                const int row = (h * 4 + mt) * 16 + n + 2 * s + qh;
                v8s Af = *(const v8s*)&myrow[(ql * 144 + row) * 8];
                acc[mt][0] = __builtin_amdgcn_mfma_f32_16x16x32_bf16(Af, Bw0, acc[mt][0], 0, 0, 0);
                acc[mt][1] = __builtin_amdgcn_mfma_f32_16x16x32_bf16(Af, Bw1, acc[mt][1], 0, 0, 0);
            }
        }
        unsigned held[8];
        #pragma unroll
        for (int mt = 0; mt < 4; mt++)
            #pragma unroll
            for (int nt = 0; nt < 2; nt++) {
                const float bb = nt ? bias1 : bias0;
                float h0  = fmaxf(fmaxf(acc[mt][nt][0], acc[mt][nt][1]) + bb, 0.f);
                float h1v = fmaxf(fmaxf(acc[mt][nt][2], acc[mt][nt][3]) + bb, 0.f);
                held[mt * 2 + nt] = pk2(h0, h1v);
            }
        #pragma unroll
        for (int mt = 0; mt < 4; mt++) {
            const int p = (h * 4 + mt) * 8 + quad * 2;
            #pragma unroll
            for (int nt = 0; nt < 2; nt++) {
                const unsigned pr = held[mt * 2 + nt];
                const int plane = nt * 2 + (n >> 3);     // conv2 ic-chunk
                const int col = n & 7;
                if (p < 60)     myrow[H1OFF + (plane * 73 + p) * 8 + col]     = (short)(pr & 0xFFFFu);
                if (p + 1 < 60) myrow[H1OFF + (plane * 73 + p + 1) * 8 + col] = (short)(pr >> 16);
            }
        }
    }
    __syncthreads();

    // ---- phase 3: conv2, raw out positions 32h..32h+31 (mt' = h*2+mt) ----
    {
        float biasv[4];
        #pragma unroll
        for (int nt = 0; nt < 4; nt++) biasv[nt] = b2g[d * 64 + nt * 16 + n];
        v4f acc[2][4];
        #pragma unroll
        for (int mt = 0; mt < 2; mt++)
            #pragma unroll
            for (int nt = 0; nt < 4; nt++) { v4f z = {0.f,0.f,0.f,0.f}; acc[mt][nt] = z; }
        for (int tap = 0; tap < 9; tap++) {
            v8s Bw[4];
            #pragma unroll
            for (int nt = 0; nt < 4; nt++)
                Bw[nt] = *(const v8s*)&w2t[(nt * 16 + n) * 288 + tap * 32 + quad * 8];
            #pragma unroll
            for (int mt = 0; mt < 2; mt++) {
                const int row = (h * 2 + mt) * 16 + n + tap;
                v8s Af = *(const v8s*)&myrow[H1OFF + (quad * 73 + row) * 8];
                #pragma unroll
                for (int nt = 0; nt < 4; nt++)
                    acc[mt][nt] = __builtin_amdgcn_mfma_f32_16x16x32_bf16(Af, Bw[nt], acc[mt][nt], 0, 0, 0);
            }
        }
        unsigned held[8];
        #pragma unroll
        for (int mt = 0; mt < 2; mt++)
            #pragma unroll
            for (int nt = 0; nt < 4; nt++) {
                float h0  = fmaxf(fmaxf(acc[mt][nt][0], acc[mt][nt][1]) + biasv[nt], 0.f);
                float h1v = fmaxf(fmaxf(acc[mt][nt][2], acc[mt][nt][3]) + biasv[nt], 0.f);
                held[mt * 4 + nt] = pk2(h0, h1v);
            }
        #pragma unroll
        for (int mt = 0; mt < 2; mt++) {
            const int p = (h * 2 + mt) * 8 + quad * 2;
            #pragma unroll
            for (int nt = 0; nt < 4; nt++) {
                const unsigned pr = held[mt * 4 + nt];
                const int oc = nt * 16 + n;
                if (p < 26) {
                    const int gs = (oc >> 3) ^ (p & 7);
                    myrow[p * 64 + gs * 8 + (oc & 7)] = (short)(pr & 0xFFFFu);
                }
                if (p + 1 < 26) {
                    const int gs = (oc >> 3) ^ ((p + 1) & 7);
                    myrow[(p + 1) * 64 + gs * 8 + (oc & 7)] = (short)(pr >> 16);
                }
            }
        }
    }
    __syncthreads();   // both rows' h2p visible

    // ---- phase 4: fc via MFMA. N col n -> block row (n&1); K over 4 waves. ----
    {
        const int lrow = (n < 12) ? n : 0;
        v4f acc = {0.f, 0.f, 0.f, 0.f};
        for (int ks = wv; ks < 52; ks += 4) {
            const int p = ks >> 1;
            const int gs = ((ks & 1) * 4 + quad) ^ (p & 7);   // match writer swizzle
            v8s A  = *(const v8s*)&fcwp[lrow * 1664 + ks * 32 + quad * 8];
            v8s Bf = *(const v8s*)&lds[(n & 1) * REGION + p * 64 + gs * 8];
            acc = __builtin_amdgcn_mfma_f32_16x16x32_bf16(A, Bf, acc, 0, 0, 0);
        }
        float* red = (float*)&lds[r * REGION + H1OFF];   // h1t dead after conv2
        *(float4*)&red[(h * 256) + lane * 4] = *(float4*)&acc;
    }
    __syncthreads();
    if (t < 64) {
        float sum[4] = {0.f, 0.f, 0.f, 0.f};
        #pragma unroll
        for (int w = 0; w < 4; w++) {
            const float* redw = (const float*)&lds[(w >> 1) * REGION + H1OFF];
            float4 v = *(const float4*)&redw[((w & 1) * 256) + lane * 4];
            sum[0] += v.x; sum[1] += v.y; sum[2] += v.z; sum[3] += v.w;
        }
        if (n < 2) {
            const float wgt = wts[(size_t)(b0 + n) * 8 + d];
            #pragma unroll
            for (int r4 = 0; r4 < 4; r4++) {
                const int l = quad * 4 + r4;
                if (l < 12) {
                    float v = fmaxf(sum[r4] + fcb[d * 12 + l], 0.f);
                    atomicAdd(&out[(size_t)(b0 + n) * 12 + l], wgt * v);
                }
            }
        }
    }
}

extern "C" void kernel_launch(void* const* d_in, const int* in_sizes, int n_in,
                              void* d_out, int out_size, void* d_ws, size_t ws_size,
                              hipStream_t stream) {
    const float* x       = (const float*)d_in[0];
    const float* weights = (const float*)d_in[1];
    const float* gamma   = (const float*)d_in[2];
    const float* beta    = (const float*)d_in[3];
    const float* w1      = (const float*)d_in[4];
    const float* b1      = (const float*)d_in[5];
    const float* w2      = (const float*)d_in[6];
    const float* b2      = (const float*)d_in[7];
    const float* fcw     = (const float*)d_in[8];
    const float* fcb     = (const float*)d_in[9];
    float* ws  = (float*)d_ws;
    float* out = (float*)d_out;

    stats_repack_kernel<<<dim3(624), 256, 0, stream>>>(x, w2, fcw, ws, out);
    fold1_kernel<<<dim3(D), 256, 0, stream>>>(w1, b1, gamma, beta, ws);
    branch_kernel<<<dim3(B / 2, D), 256, 0, stream>>>(x, b2, fcb, weights, ws, out);
}

// Round 13
// 233.431 us; speedup vs baseline: 1.4770x; 1.4770x over previous
//
#include <hip/hip_runtime.h>
#include <hip/hip_bf16.h>

#define D 8
#define L 12
#define C 9
#define W 128
#define B 4096
#define EPS 1e-5f

typedef __attribute__((ext_vector_type(8))) short v8s;   // 8 x bf16
typedef __attribute__((ext_vector_type(4))) float v4f;   // 4 x f32 acc

// Workspace layout (in floats)
#define OFF_STATS 0        // [64 slices][18] per-slice partials (sum[9], sumsq[9])
#define OFF_B1E   1152     // fp32 [D][32] folded conv1 bias
#define OFF_W1T   1408     // bf16 [D][32 o][10 tap][16 c]  = 40960 halfs
#define OFF_W2T   21888    // bf16 [D][64 o][9 tap][32 ic]  = 147456 halfs
#define OFF_FCWP  95616    // bf16 [D][12 l][1664 k=p*64+o] = 159744 halfs

// Per-wave LDS region (shorts). Serial aliasing within one wave's region:
//   xb  [2 ql][144 row][8]  = 2304
//   h1t [4 icq][73 row][8]  = 2336   (padded 73: conv1 b16 writes bank-free)
//   h2p [1672] + red f32[64][4] @1672 = 2184
#define REGION 2336

__device__ inline unsigned short f2bf(float f) {
    unsigned u = __builtin_bit_cast(unsigned, f);
    u += 0x7FFFu + ((u >> 16) & 1u);                 // round-nearest-even
    return (unsigned short)(u >> 16);
}
__device__ inline unsigned pk2(float a, float b) {
    float2 f2; f2.x = a; f2.y = b;
    __hip_bfloat162 h = __float22bfloat162_rn(f2);   // v_cvt_pk_bf16_f32
    unsigned u; __builtin_memcpy(&u, &h, 4);
    return u;
}

// ---------------------------------------------------------------------------
// Kernel 1: stats partials (blocks 0..575) + w2t/fcwp repack (576..615)
// + d_out zeroing (616..623; replaces the hipMemsetAsync graph node — safe
// because this kernel fully precedes branch_kernel in the stream).
// ---------------------------------------------------------------------------
__global__ void stats_repack_kernel(const float* __restrict__ x,
                                    const float* __restrict__ w2,
                                    const float* __restrict__ fcw,
                                    float* __restrict__ ws,
                                    float* __restrict__ out) {
    const int t = threadIdx.x;
    __shared__ float redS[8];
    if (blockIdx.x < 576) {
        const int c = blockIdx.x % 9;
        const int slice = blockIdx.x / 9;
        const int w4 = t & 31, br = t >> 5;
        const float4* x4 = (const float4*)x;
        float s = 0.f, s2 = 0.f;
        for (int b = slice * 8 + br; b < B; b += 64 * 8) {
            float4 v = x4[(size_t)b * 288 + c * 32 + w4];
            s  += v.x + v.y + v.z + v.w;
            s2 += v.x * v.x + v.y * v.y + v.z * v.z + v.w * v.w;
        }
        for (int off = 32; off >= 1; off >>= 1) {
            s  += __shfl_down(s, off);
            s2 += __shfl_down(s2, off);
        }
        if ((t & 63) == 0) { redS[(t >> 6) * 2] = s; redS[(t >> 6) * 2 + 1] = s2; }
        __syncthreads();
        if (t == 0) {
            ws[OFF_STATS + slice * 18 + c]     = redS[0] + redS[2] + redS[4] + redS[6];
            ws[OFF_STATS + slice * 18 + 9 + c] = redS[1] + redS[3] + redS[5] + redS[7];
        }
    } else if (blockIdx.x < 616) {
        const int i0 = blockIdx.x - 576;
        const int d = i0 / 5, part = i0 % 5;
        short* w2t  = (short*)(ws + OFF_W2T);
        short* fcwp = (short*)(ws + OFF_FCWP);
        if (part < 2) {
            for (int i = part * 256 + t; i < 64 * 9 * 32; i += 512) {
                int o = i / 288, r = i % 288, tap = r / 32, ic = r & 31;
                w2t[(size_t)d * 18432 + i] =
                    (short)f2bf(w2[(((size_t)(d * 64 + o)) * 32 + ic) * 9 + tap]);
            }
        } else {
            for (int i = (part - 2) * 256 + t; i < 12 * 1664; i += 768) {
                int l = i / 1664, k = i % 1664, p = k >> 6, o = k & 63;
                fcwp[((size_t)d * 12) * 1664 + i] =
                    (short)f2bf(fcw[((size_t)(d * 12 + l)) * 1664 + o * 26 + p]);
            }
        }
    } else {
        // zero d_out (B*L = 49152 floats over 8 blocks)
        const int base = (blockIdx.x - 616) * 6144;
        float4 z; z.x = z.y = z.z = z.w = 0.f;
        float4* o4 = (float4*)(out + base);
        for (int i = t; i < 1536; i += 256) o4[i] = z;
    }
}

// ---------------------------------------------------------------------------
// Kernel 2: reduce slice partials -> BN scale/shift; fold into conv1 weights.
// ---------------------------------------------------------------------------
__global__ void fold1_kernel(const float* __restrict__ w1, const float* __restrict__ b1,
                             const float* __restrict__ gamma, const float* __restrict__ beta,
                             float* __restrict__ ws) {
    const int d = blockIdx.x, t = threadIdx.x;
    __shared__ float g[9], bt[9];
    if (t < 64) {
        for (int c = 0; c < 9; c++) {
            float s  = ws[OFF_STATS + t * 18 + c];
            float s2 = ws[OFF_STATS + t * 18 + 9 + c];
            for (int off = 32; off >= 1; off >>= 1) {
                s  += __shfl_down(s, off);
                s2 += __shfl_down(s2, off);
            }
            if (t == 0) {
                const float N = (float)B * (float)W;
                float m  = s / N;
                float vv = s2 / N - m * m;
                float inv = rsqrtf(vv + EPS);
                float gg = gamma[d * 9 + c] * inv;
                g[c] = gg; bt[c] = beta[d * 9 + c] - gg * m;
            }
        }
    }
    __syncthreads();
    const int o = t >> 3, sub = t & 7;
    short* w1t = (short*)(ws + OFF_W1T);
    short* dst = w1t + (size_t)d * 5120 + o * 160;
    const float* src = w1 + ((size_t)(d * 32 + o)) * 81;
    float bias_part = 0.f;
    for (int tap = sub; tap < 10; tap += 8) {
        for (int c = 0; c < 16; c++) {
            float v = 0.f;
            if (tap < 9 && c < 9) {
                float wv = src[c * 9 + tap];
                v = wv * g[c];
                bias_part += wv * bt[c];
            }
            dst[tap * 16 + c] = (short)f2bf(v);
        }
    }
    bias_part += __shfl_xor(bias_part, 1);
    bias_part += __shfl_xor(bias_part, 2);
    bias_part += __shfl_xor(bias_part, 4);
    if (sub == 0) ws[OFF_B1E + d * 32 + o] = b1[d * 32 + o] + bias_part;
}

// ---------------------------------------------------------------------------
// Kernel 3: the branch. Grid (B/4, D) — one domain per block (R10's per-block
// domain loop regressed: scratch/loop-state + L1 thrash; keep same-domain-
// concurrent). Block = 4 batch rows, 256 threads (4 waves); wave wv owns
// batch row wv. Conv pipeline is wave-local & barrier-free (region aliasing
// + reg-parked epilogues); only FC syncs. h1t planes padded to 73 rows ->
// conv1 b16 writes hit all 32 banks at 2 lanes/bank (free).
// __launch_bounds__(256,4): (256,6) caused catastrophic scratch spills (R8);
// (256,5) + halved acc tiles lost ILP and regressed 164->282 (R12).
// ---------------------------------------------------------------------------
__global__ __launch_bounds__(256, 4)
void branch_kernel(const float* __restrict__ x,
                   const float* __restrict__ b2g,
                   const float* __restrict__ fcb,
                   const float* __restrict__ wts,
                   const float* __restrict__ ws,
                   float* __restrict__ out) {
    const int t = threadIdx.x;
    const int lane = t & 63;
    const int wv = t >> 6;                       // 0..3
    const int d = blockIdx.y;
    const int b0 = blockIdx.x * 4;
    const short* w1t  = (const short*)(ws + OFF_W1T) + (size_t)d * 5120;
    const short* w2t  = (const short*)(ws + OFF_W2T) + (size_t)d * 18432;
    const short* fcwp = (const short*)(ws + OFF_FCWP) + (size_t)d * 12 * 1664;
    const float* b1e  = ws + OFF_B1E + d * 32;

    __shared__ __align__(16) short lds[4 * REGION];   // 18688 B
    short* myr = &lds[wv * REGION];

    const int n = lane & 15, quad = lane >> 4;

    // ---- phase 1: x -> bf16 transposed into own xb (no barrier) ----
    {
        const float* xrow = x + (size_t)(b0 + wv) * 1152;
        #pragma unroll
        for (int rep = 0; rep < 2; rep++) {
            const int w = lane + rep * 64;
            float v[9];
            #pragma unroll
            for (int c = 0; c < 9; c++) v[c] = xrow[c * 128 + w];
            uint4 lo, hi;
            lo.x = pk2(v[0], v[1]); lo.y = pk2(v[2], v[3]);
            lo.z = pk2(v[4], v[5]); lo.w = pk2(v[6], v[7]);
            hi.x = (unsigned)(unsigned short)f2bf(v[8]); hi.y = 0; hi.z = 0; hi.w = 0;
            *(uint4*)&myr[(0 * 144 + w) * 8] = lo;
            *(uint4*)&myr[(1 * 144 + w) * 8] = hi;
        }
        if (lane < 16) {   // zero rows 128..143, both ql planes
            uint4 z; z.x = z.y = z.z = z.w = 0;
            *(uint4*)&myr[(0 * 144 + 128 + lane) * 8] = z;
            *(uint4*)&myr[(1 * 144 + 128 + lane) * 8] = z;
        }
    }

    // ---- phase 2: conv1 (A=xb pos, B=w1 oc). acc[8][2] -> park -> h1t ----
    {
        const int qh = quad >> 1, ql = quad & 1;
        const float bias0 = b1e[n], bias1 = b1e[16 + n];
        v4f acc[8][2];
        #pragma unroll
        for (int mt = 0; mt < 8; mt++)
            #pragma unroll
            for (int nt = 0; nt < 2; nt++) { v4f z = {0.f,0.f,0.f,0.f}; acc[mt][nt] = z; }
        #pragma unroll
        for (int s = 0; s < 5; s++) {
            v8s Bw0 = *(const v8s*)&w1t[n * 160 + (2 * s + qh) * 16 + ql * 8];
            v8s Bw1 = *(const v8s*)&w1t[(16 + n) * 160 + (2 * s + qh) * 16 + ql * 8];
            #pragma unroll
            for (int mt = 0; mt < 8; mt++) {
                const int row = mt * 16 + n + 2 * s + qh;
                v8s Af = *(const v8s*)&myr[(ql * 144 + row) * 8];
                acc[mt][0] = __builtin_amdgcn_mfma_f32_16x16x32_bf16(Af, Bw0, acc[mt][0], 0, 0, 0);
                acc[mt][1] = __builtin_amdgcn_mfma_f32_16x16x32_bf16(Af, Bw1, acc[mt][1], 0, 0, 0);
            }
        }
        unsigned held[16];
        #pragma unroll
        for (int mt = 0; mt < 8; mt++)
            #pragma unroll
            for (int nt = 0; nt < 2; nt++) {
                const float bb = nt ? bias1 : bias0;
                float h0  = fmaxf(fmaxf(acc[mt][nt][0], acc[mt][nt][1]) + bb, 0.f);
                float h1v = fmaxf(fmaxf(acc[mt][nt][2], acc[mt][nt][3]) + bb, 0.f);
                held[mt * 2 + nt] = pk2(h0, h1v);
            }
        #pragma unroll
        for (int mt = 0; mt < 8; mt++) {
            const int p = mt * 8 + quad * 2;
            #pragma unroll
            for (int nt = 0; nt < 2; nt++) {
                const unsigned pr = held[mt * 2 + nt];
                const int plane = nt * 2 + (n >> 3);     // conv2 ic-chunk
                const int col = n & 7;
                if (p < 60)     myr[(plane * 73 + p) * 8 + col]     = (short)(pr & 0xFFFFu);
                if (p + 1 < 60) myr[(plane * 73 + p + 1) * 8 + col] = (short)(pr >> 16);
            }
        }
    }

    // ---- phase 3: conv2 (A=h1t pos, B=w2 oc). acc[4][4] -> park -> h2p ----
    {
        float biasv[4];
        #pragma unroll
        for (int nt = 0; nt < 4; nt++) biasv[nt] = b2g[d * 64 + nt * 16 + n];
        v4f acc[4][4];
        #pragma unroll
        for (int mt = 0; mt < 4; mt++)
            #pragma unroll
            for (int nt = 0; nt < 4; nt++) { v4f z = {0.f,0.f,0.f,0.f}; acc[mt][nt] = z; }
        for (int tap = 0; tap < 9; tap++) {
            v8s Bw[4];
            #pragma unroll
            for (int nt = 0; nt < 4; nt++)
                Bw[nt] = *(const v8s*)&w2t[(nt * 16 + n) * 288 + tap * 32 + quad * 8];
            #pragma unroll
            for (int mt = 0; mt < 4; mt++) {
                const int row = mt * 16 + n + tap;
                v8s Af = *(const v8s*)&myr[(quad * 73 + row) * 8];
                #pragma unroll
                for (int nt = 0; nt < 4; nt++)
                    acc[mt][nt] = __builtin_amdgcn_mfma_f32_16x16x32_bf16(Af, Bw[nt], acc[mt][nt], 0, 0, 0);
            }
        }
        unsigned held[16];
        #pragma unroll
        for (int mt = 0; mt < 4; mt++)
            #pragma unroll
            for (int nt = 0; nt < 4; nt++) {
                float h0  = fmaxf(fmaxf(acc[mt][nt][0], acc[mt][nt][1]) + biasv[nt], 0.f);
                float h1v = fmaxf(fmaxf(acc[mt][nt][2], acc[mt][nt][3]) + biasv[nt], 0.f);
                held[mt * 4 + nt] = pk2(h0, h1v);
            }
        #pragma unroll
        for (int mt = 0; mt < 4; mt++) {
            const int p = mt * 8 + quad * 2;
            #pragma unroll
            for (int nt = 0; nt < 4; nt++) {
                const unsigned pr = held[mt * 4 + nt];
                const int oc = nt * 16 + n;
                if (p < 26) {
                    const int gs = (oc >> 3) ^ (p & 7);
                    myr[p * 64 + gs * 8 + (oc & 7)] = (short)(pr & 0xFFFFu);
                }
                if (p + 1 < 26) {
                    const int gs = (oc >> 3) ^ ((p + 1) & 7);
                    myr[(p + 1) * 64 + gs * 8 + (oc & 7)] = (short)(pr >> 16);
                }
            }
        }
    }
    __syncthreads();   // h2p of all 4 waves must be visible

    // ---- phase 4: fc via MFMA (cross-wave h2p reads), red in own region ----
    {
        const int lrow = (n < 12) ? n : 0;
        v4f acc = {0.f, 0.f, 0.f, 0.f};
        for (int ks = wv; ks < 52; ks += 4) {
            const int p = ks >> 1;
            const int gs = ((ks & 1) * 4 + quad) ^ (p & 7);   // match writer swizzle
            v8s A  = *(const v8s*)&fcwp[lrow * 1664 + ks * 32 + quad * 8];
            v8s Bf = *(const v8s*)&lds[(n & 3) * REGION + p * 64 + gs * 8];
            acc = __builtin_amdgcn_mfma_f32_16x16x32_bf16(A, Bf, acc, 0, 0, 0);
        }
        float* red = (float*)(myr + 1672);        // own region, above h2p data
        *(float4*)&red[lane * 4] = *(float4*)&acc;
    }
    __syncthreads();
    if (t < 64) {
        float sum[4] = {0.f, 0.f, 0.f, 0.f};
        #pragma unroll
        for (int w = 0; w < 4; w++) {
            const float* redw = (const float*)(&lds[w * REGION + 1672]);
            float4 v = *(const float4*)&redw[lane * 4];
            sum[0] += v.x; sum[1] += v.y; sum[2] += v.z; sum[3] += v.w;
        }
        if (n < 4) {
            const float wgt = wts[(size_t)(b0 + n) * 8 + d];
            #pragma unroll
            for (int r = 0; r < 4; r++) {
                const int l = quad * 4 + r;
                if (l < 12) {
                    float v = fmaxf(sum[r] + fcb[d * 12 + l], 0.f);
                    atomicAdd(&out[(size_t)(b0 + n) * 12 + l], wgt * v);
                }
            }
        }
    }
}

extern "C" void kernel_launch(void* const* d_in, const int* in_sizes, int n_in,
                              void* d_out, int out_size, void* d_ws, size_t ws_size,
                              hipStream_t stream) {
    const float* x       = (const float*)d_in[0];
    const float* weights = (const float*)d_in[1];
    const float* gamma   = (const float*)d_in[2];
    const float* beta    = (const float*)d_in[3];
    const float* w1      = (const float*)d_in[4];
    const float* b1      = (const float*)d_in[5];
    const float* w2      = (const float*)d_in[6];
    const float* b2      = (const float*)d_in[7];
    const float* fcw     = (const float*)d_in[8];
    const float* fcb     = (const float*)d_in[9];
    float* ws  = (float*)d_ws;
    float* out = (float*)d_out;

    stats_repack_kernel<<<dim3(624), 256, 0, stream>>>(x, w2, fcw, ws, out);
    fold1_kernel<<<dim3(D), 256, 0, stream>>>(w1, b1, gamma, beta, ws);
    branch_kernel<<<dim3(B / 4, D), 256, 0, stream>>>(x, b2, fcb, weights, ws, out);
}